// Round 5
// baseline (429.768 us; speedup 1.0000x reference)
//
#include <hip/hip_runtime.h>

typedef __attribute__((ext_vector_type(8))) short bf16x8;
typedef __attribute__((ext_vector_type(4))) float f32x4;

static __device__ __forceinline__ unsigned short f2bf(float f) {
    unsigned int u = __builtin_bit_cast(unsigned int, f);
    u += 0x7fffu + ((u >> 16) & 1u);          // round-to-nearest-even
    return (unsigned short)(u >> 16);
}
static __device__ __forceinline__ float bf2f(unsigned short h) {
    unsigned int u = ((unsigned int)h) << 16;
    return __builtin_bit_cast(float, u);
}

// ---------------- prep kernels ----------------

__global__ void cvt_x_kernel(const float* __restrict__ x, unsigned short* __restrict__ xb, int total8) {
    int i = blockIdx.x * blockDim.x + threadIdx.x;
    if (i >= total8) return;
    const float4* p = reinterpret_cast<const float4*>(x) + (size_t)i * 2;
    float4 a = p[0], b = p[1];
    bf16x8 o;
    o[0] = (short)f2bf(a.x); o[1] = (short)f2bf(a.y); o[2] = (short)f2bf(a.z); o[3] = (short)f2bf(a.w);
    o[4] = (short)f2bf(b.x); o[5] = (short)f2bf(b.y); o[6] = (short)f2bf(b.z); o[7] = (short)f2bf(b.w);
    reinterpret_cast<bf16x8*>(xb)[i] = o;
}

// W [k][cin][cout] f32 -> WT [k][cout][cin] bf16, both weight tensors in one launch
__global__ void cvt_w_kernel(const float* __restrict__ w1, const float* __restrict__ w2,
                             unsigned short* __restrict__ wt1, unsigned short* __restrict__ wt2) {
    int i = blockIdx.x * blockDim.x + threadIdx.x;
    if (i >= 2 * 27 * 4096) return;
    const float* w = (i < 27 * 4096) ? w1 : w2;
    unsigned short* wt = (i < 27 * 4096) ? wt1 : wt2;
    int j = (i < 27 * 4096) ? i : i - 27 * 4096;
    int k = j >> 12;
    int cout = (j >> 6) & 63;
    int cin = j & 63;
    wt[j] = f2bf(w[((size_t)(k * 64 + cin)) * 64 + cout]);
}

// ---------------- gathered GEMM (octree conv), depth-2 pipeline ----------------
// Block = 64 rows x 64 cols; 4 waves, wave w owns rows (w&1)*32..+31, cols (w>>1)*32..+31.
// 3 LDS A-buffers (mod-3), prefetch distance 2. Each ISSUE = exactly 6 VMEM ops
// (2 global_load_lds gathers, then 4 B-frag loads); steady-state wait = vmcnt(12).
// Live B register sets = 3 x 16 = 48 VGPR (fits; round-4's 64 did not).
__global__ __launch_bounds__(256, 4) void conv_mfma(
    const unsigned short* __restrict__ xb,   // [n][64] bf16
    const int* __restrict__ nh,              // [n][27] neighbor indices
    const unsigned short* __restrict__ wt,   // [27][64][64] bf16 (cout-major)
    unsigned short* __restrict__ y,          // [n][64] bf16 (raw conv out)
    float* __restrict__ pS,                  // [64][grid] transposed partials
    float* __restrict__ pQ,                  // [64][grid]
    int n)
{
    __shared__ unsigned short Atile[3][4096];   // 3 x (64 rows x 64 shorts) = 24 KB
    __shared__ int lidx[27 * 64];               // neighbor indices (6.9 KB)

    const int tid  = threadIdx.x;
    const int wid  = tid >> 6;
    const int lane = tid & 63;
    const int lr   = lane & 15;
    const int lg   = lane >> 4;
    const int base = blockIdx.x * 64;
    const int rw   = (wid & 1) * 32;            // wave's row offset in tile
    const int cw   = (wid >> 1) * 32;           // wave's col offset

    // stage neighbor indices; after this, idx reads are LDS-only (out of vmcnt queue)
    for (int j = tid; j < 27 * 64; j += 256) {
        int row = j / 27;
        int kk  = j - row * 27;
        int gr  = base + row; if (gr >= n) gr = n - 1;
        lidx[j] = nh[(size_t)gr * 27 + kk];
    }
    __syncthreads();   // full drain: vmcnt queue empty entering the pipeline

    // staging geometry: rows (tid>>3) [+32], 16B slot (tid&7), XOR-swizzled source
    const int srow = tid >> 3;
    const int xoff = ((tid & 7) ^ (srow & 7)) * 8;
    const int so0  = srow * 27;
    const int so1  = (srow + 32) * 27;

    f32x4 acc[2][2];
    acc[0][0] = (f32x4){0.f,0.f,0.f,0.f}; acc[0][1] = (f32x4){0.f,0.f,0.f,0.f};
    acc[1][0] = (f32x4){0.f,0.f,0.f,0.f}; acc[1][1] = (f32x4){0.f,0.f,0.f,0.f};

    // B frag base: lane -> cout = cw + cf*16 + lr, cin = h*32 + lg*8
    const unsigned short* wB = wt + (size_t)(cw + lr) * 64 + lg * 8;
    bf16x8 Breg[3][4];   // [buffer][cf*2+h] — compile-time indices after unroll

#define ISSUE(kk) do {                                                                \
        const int i0_ = lidx[so0 + (kk)];                                             \
        const int i1_ = lidx[so1 + (kk)];                                             \
        __builtin_amdgcn_global_load_lds(                                             \
            (const __attribute__((address_space(1))) unsigned int*)(xb + (size_t)i0_ * 64 + xoff), \
            (__attribute__((address_space(3))) unsigned int*)(&Atile[(kk)%3][wid * 512]), 16, 0, 0);    \
        __builtin_amdgcn_global_load_lds(                                             \
            (const __attribute__((address_space(1))) unsigned int*)(xb + (size_t)i1_ * 64 + xoff), \
            (__attribute__((address_space(3))) unsigned int*)(&Atile[(kk)%3][2048 + wid * 512]), 16, 0, 0); \
        Breg[(kk)%3][0] = *reinterpret_cast<const bf16x8*>(wB + (kk)*4096);           \
        Breg[(kk)%3][1] = *reinterpret_cast<const bf16x8*>(wB + (kk)*4096 + 32);      \
        Breg[(kk)%3][2] = *reinterpret_cast<const bf16x8*>(wB + (kk)*4096 + 1024);    \
        Breg[(kk)%3][3] = *reinterpret_cast<const bf16x8*>(wB + (kk)*4096 + 1056);    \
    } while (0)

#define COMPUTE_BODY(kk) do {                                                         \
        const unsigned short* At = &Atile[(kk)%3][0];                                 \
        _Pragma("unroll")                                                             \
        for (int rf = 0; rf < 2; ++rf) {                                              \
            const int row_ = rw + rf * 16 + lr;                                       \
            const int sw_  = (row_ & 7) * 8;                                          \
            bf16x8 A0 = *reinterpret_cast<const bf16x8*>(&At[row_ * 64 + ((lg * 8) ^ sw_)]);        \
            bf16x8 A1 = *reinterpret_cast<const bf16x8*>(&At[row_ * 64 + (((4 + lg) * 8) ^ sw_)]);  \
            acc[rf][0] = __builtin_amdgcn_mfma_f32_16x16x32_bf16(A0, Breg[(kk)%3][0], acc[rf][0], 0, 0, 0); \
            acc[rf][0] = __builtin_amdgcn_mfma_f32_16x16x32_bf16(A1, Breg[(kk)%3][1], acc[rf][0], 0, 0, 0); \
            acc[rf][1] = __builtin_amdgcn_mfma_f32_16x16x32_bf16(A0, Breg[(kk)%3][2], acc[rf][1], 0, 0, 0); \
            acc[rf][1] = __builtin_amdgcn_mfma_f32_16x16x32_bf16(A1, Breg[(kk)%3][3], acc[rf][1], 0, 0, 0); \
        }                                                                             \
    } while (0)

#define PHASE(kk, VMSTR) do {                                                         \
        asm volatile("s_waitcnt " VMSTR ::: "memory");                                \
        __builtin_amdgcn_s_barrier();                                                 \
        __builtin_amdgcn_sched_barrier(0);                                            \
        COMPUTE_BODY(kk);                                                             \
        asm volatile("s_waitcnt lgkmcnt(0)" ::: "memory");                            \
        __builtin_amdgcn_sched_barrier(0);                                            \
        __builtin_amdgcn_s_barrier();                                                 \
    } while (0)

    // prologue: taps 0,1 in flight (12 VMEM ops)
    ISSUE(0); ISSUE(1);

    #pragma unroll
    for (int k = 0; k < 25; ++k) {
        ISSUE(k + 2);                 // queue: taps k..k+2 = 18 ops
        PHASE(k, "vmcnt(12)");        // retire tap k's 6; k+1,k+2 stay in flight
    }
    PHASE(25, "vmcnt(6)");
    PHASE(26, "vmcnt(0)");
#undef ISSUE
#undef COMPUTE_BODY
#undef PHASE

    // epilogue: store bf16 conv output + per-channel partial stats
    float s1[2] = {0.f, 0.f}, s2[2] = {0.f, 0.f};
    #pragma unroll
    for (int rf = 0; rf < 2; ++rf) {
        #pragma unroll
        for (int rg = 0; rg < 4; ++rg) {
            const int row = base + rw + rf * 16 + lg * 4 + rg;   // C/D: row=(lane>>4)*4+reg
            if (row < n) {
                #pragma unroll
                for (int cf = 0; cf < 2; ++cf) {
                    const float v = acc[rf][cf][rg];
                    s1[cf] += v;
                    s2[cf] += v * v;
                    y[(size_t)row * 64 + cw + cf * 16 + lr] = f2bf(v);  // col = cw+cf*16+lr
                }
            }
        }
    }
    #pragma unroll
    for (int cf = 0; cf < 2; ++cf) {
        s1[cf] += __shfl_xor(s1[cf], 16); s1[cf] += __shfl_xor(s1[cf], 32);
        s2[cf] += __shfl_xor(s2[cf], 16); s2[cf] += __shfl_xor(s2[cf], 32);
    }
    // combine the two row-half waves per column (reuse dead Atile as scratch)
    float* fs = (float*)&Atile[0][0];   // fs[0..127]=s1, fs[128..255]=s2
    __syncthreads();
    if (lane < 16) {
        fs[wid * 32 + lr]            = s1[0];
        fs[wid * 32 + 16 + lr]       = s1[1];
        fs[128 + wid * 32 + lr]      = s2[0];
        fs[128 + wid * 32 + 16 + lr] = s2[1];
    }
    __syncthreads();
    if (tid < 64) {
        const int hi = tid >> 5, cl = tid & 31;
        const float S = fs[hi * 64 + cl] + fs[hi * 64 + 32 + cl];
        const float Q = fs[128 + hi * 64 + cl] + fs[128 + hi * 64 + 32 + cl];
        pS[(size_t)tid * gridDim.x + blockIdx.x] = S;
        pQ[(size_t)tid * gridDim.x + blockIdx.x] = Q;
    }
}

// ---------------- BN finalize: parallel reduce of partials ----------------
__global__ __launch_bounds__(256) void bn_stats_kernel(
        const float* __restrict__ pS, const float* __restrict__ pQ,
        const float* __restrict__ gamma, const float* __restrict__ beta,
        float* __restrict__ bnp, int nb, float invN) {
    const int c = blockIdx.x;          // channel
    const int tid = threadIdx.x;
    float S = 0.f, Q = 0.f;
    for (int b = tid; b < nb; b += 256) {
        S += pS[(size_t)c * nb + b];
        Q += pQ[(size_t)c * nb + b];
    }
    #pragma unroll
    for (int o = 1; o < 64; o <<= 1) {
        S += __shfl_xor(S, o);
        Q += __shfl_xor(Q, o);
    }
    __shared__ float sh[8];
    if ((tid & 63) == 0) { sh[(tid >> 6) * 2] = S; sh[(tid >> 6) * 2 + 1] = Q; }
    __syncthreads();
    if (tid == 0) {
        S = sh[0] + sh[2] + sh[4] + sh[6];
        Q = sh[1] + sh[3] + sh[5] + sh[7];
        const float mean = S * invN;
        const float var  = Q * invN - mean * mean;
        const float sc   = gamma[c] * rsqrtf(var + 1e-5f);
        bnp[c]      = sc;
        bnp[64 + c] = beta[c] - mean * sc;
    }
}

// ---------------- BN+ReLU -> bf16 (input of conv2) ----------------
__global__ void bn_relu_kernel(const unsigned short* __restrict__ y, const float* __restrict__ bnp,
                               unsigned short* __restrict__ yn, int total8) {
    int i = blockIdx.x * blockDim.x + threadIdx.x;
    if (i >= total8) return;
    bf16x8 v = reinterpret_cast<const bf16x8*>(y)[i];
    int c0 = (i * 8) & 63;
    bf16x8 o;
    #pragma unroll
    for (int j = 0; j < 8; ++j) {
        float f = bf2f((unsigned short)v[j]) * bnp[c0 + j] + bnp[64 + c0 + j];
        f = fmaxf(f, 0.f);
        o[j] = (short)f2bf(f);
    }
    reinterpret_cast<bf16x8*>(yn)[i] = o;
}

// ---------------- final: BN2 + residual + ReLU -> f32 out, plus depth ----------------
__global__ void final_kernel(const unsigned short* __restrict__ y2, const float* __restrict__ x,
                             const float* __restrict__ bnp, const int* __restrict__ depth,
                             float* __restrict__ out, int total8, int n) {
    int i = blockIdx.x * blockDim.x + threadIdx.x;
    if (i == 0) out[(size_t)n * 64] = (float)depth[0];
    if (i >= total8) return;
    bf16x8 v = reinterpret_cast<const bf16x8*>(y2)[i];
    const float4* xp = reinterpret_cast<const float4*>(x) + (size_t)i * 2;
    float4 xa = xp[0], xbv = xp[1];
    int c0 = (i * 8) & 63;
    float r[8];
    #pragma unroll
    for (int j = 0; j < 8; ++j)
        r[j] = bf2f((unsigned short)v[j]) * bnp[c0 + j] + bnp[64 + c0 + j];
    r[0] += xa.x;  r[1] += xa.y;  r[2] += xa.z;  r[3] += xa.w;
    r[4] += xbv.x; r[5] += xbv.y; r[6] += xbv.z; r[7] += xbv.w;
    float4* op = reinterpret_cast<float4*>(out) + (size_t)i * 2;
    float4 o0 = {fmaxf(r[0], 0.f), fmaxf(r[1], 0.f), fmaxf(r[2], 0.f), fmaxf(r[3], 0.f)};
    float4 o1 = {fmaxf(r[4], 0.f), fmaxf(r[5], 0.f), fmaxf(r[6], 0.f), fmaxf(r[7], 0.f)};
    op[0] = o0;
    op[1] = o1;
}

extern "C" void kernel_launch(void* const* d_in, const int* in_sizes, int n_in,
                              void* d_out, int out_size, void* d_ws, size_t ws_size,
                              hipStream_t stream) {
    const float* x     = (const float*)d_in[0];
    const int*   neigh = (const int*)d_in[1];
    const int*   depth = (const int*)d_in[2];
    const float* W1    = (const float*)d_in[3];
    const float* g1    = (const float*)d_in[4];
    const float* b1    = (const float*)d_in[5];
    const float* W2    = (const float*)d_in[6];
    const float* g2    = (const float*)d_in[7];
    const float* b2    = (const float*)d_in[8];
    float* out = (float*)d_out;

    const int n      = in_sizes[0] / 64;   // 200000
    const int total8 = in_sizes[0] / 8;    // N*C/8
    const int nb     = (n + 63) / 64;      // conv grid (3125)

    char* ws = (char*)d_ws;
    size_t off = 0;
    auto carve = [&](size_t bytes) -> char* {
        char* p = ws + off;
        off += (bytes + 255) & ~((size_t)255);
        return p;
    };
    unsigned short* bufA = (unsigned short*)carve((size_t)n * 64 * 2); // xb, later y1n
    unsigned short* bufB = (unsigned short*)carve((size_t)n * 64 * 2); // y1, later y2
    unsigned short* w1t  = (unsigned short*)carve(27 * 4096 * 2);
    unsigned short* w2t  = (unsigned short*)carve(27 * 4096 * 2);
    float*          pS   = (float*)carve((size_t)nb * 64 * 4);
    float*          pQ   = (float*)carve((size_t)nb * 64 * 4);
    float*          bnp1 = (float*)carve(128 * 4);
    float*          bnp2 = (float*)carve(128 * 4);

    const int gcvt = (total8 + 255) / 256;
    const int gw   = (2 * 27 * 4096 + 255) / 256;
    const float invN = 1.0f / (float)n;

    cvt_x_kernel<<<gcvt, 256, 0, stream>>>(x, bufA, total8);
    cvt_w_kernel<<<gw, 256, 0, stream>>>(W1, W2, w1t, w2t);

    conv_mfma<<<nb, 256, 0, stream>>>(bufA, neigh, w1t, bufB, pS, pQ, n);
    bn_stats_kernel<<<64, 256, 0, stream>>>(pS, pQ, g1, b1, bnp1, nb, invN);
    bn_relu_kernel<<<gcvt, 256, 0, stream>>>(bufB, bnp1, bufA, total8);

    conv_mfma<<<nb, 256, 0, stream>>>(bufA, neigh, w2t, bufB, pS, pQ, n);
    bn_stats_kernel<<<64, 256, 0, stream>>>(pS, pQ, g2, b2, bnp2, nb, invN);
    final_kernel<<<gcvt, 256, 0, stream>>>(bufB, x, bnp2, depth, out, total8, n);
}

// Round 6
// 282.474 us; speedup vs baseline: 1.5214x; 1.5214x over previous
//
#include <hip/hip_runtime.h>

typedef __attribute__((ext_vector_type(8))) short bf16x8;
typedef __attribute__((ext_vector_type(4))) float f32x4;

static __device__ __forceinline__ unsigned short f2bf(float f) {
    unsigned int u = __builtin_bit_cast(unsigned int, f);
    u += 0x7fffu + ((u >> 16) & 1u);          // round-to-nearest-even
    return (unsigned short)(u >> 16);
}
static __device__ __forceinline__ float bf2f(unsigned short h) {
    unsigned int u = ((unsigned int)h) << 16;
    return __builtin_bit_cast(float, u);
}

// ---------------- prep kernels ----------------

__global__ void cvt_x_kernel(const float* __restrict__ x, unsigned short* __restrict__ xb, int total8) {
    int i = blockIdx.x * blockDim.x + threadIdx.x;
    if (i >= total8) return;
    const float4* p = reinterpret_cast<const float4*>(x) + (size_t)i * 2;
    float4 a = p[0], b = p[1];
    bf16x8 o;
    o[0] = (short)f2bf(a.x); o[1] = (short)f2bf(a.y); o[2] = (short)f2bf(a.z); o[3] = (short)f2bf(a.w);
    o[4] = (short)f2bf(b.x); o[5] = (short)f2bf(b.y); o[6] = (short)f2bf(b.z); o[7] = (short)f2bf(b.w);
    reinterpret_cast<bf16x8*>(xb)[i] = o;
}

// W [k][cin][cout] f32 -> WT [k][cout][cin] bf16, both weight tensors in one launch
__global__ void cvt_w_kernel(const float* __restrict__ w1, const float* __restrict__ w2,
                             unsigned short* __restrict__ wt1, unsigned short* __restrict__ wt2) {
    int i = blockIdx.x * blockDim.x + threadIdx.x;
    if (i >= 2 * 27 * 4096) return;
    const float* w = (i < 27 * 4096) ? w1 : w2;
    unsigned short* wt = (i < 27 * 4096) ? wt1 : wt2;
    int j = (i < 27 * 4096) ? i : i - 27 * 4096;
    int k = j >> 12;
    int cout = (j >> 6) & 63;
    int cin = j & 63;
    wt[j] = f2bf(w[((size_t)(k * 64 + cin)) * 64 + cout]);
}

// ---------------- gathered GEMM (octree conv), depth-2, rolled modulo-scheduled ----------------
// Block = 64 rows x 64 cols. 4 waves; wave w owns col-quarter w*16..w*16+15 (round-3 layout).
// 3 LDS A-buffers + 3 named B-reg pairs; prefetch distance 2. ISSUE = 4 VMEM ops
// (2 B-frag loads then 2 global_load_lds); steady-state wait = vmcnt(8); tail 8/4/0.
// Loop stays ROLLED (8 iters x 3 phases) - rounds 4/5 showed full unroll kills I-cache.
__global__ __launch_bounds__(256, 5) void conv_mfma(
    const unsigned short* __restrict__ xb,   // [n][64] bf16
    const int* __restrict__ nh,              // [n][27] neighbor indices
    const unsigned short* __restrict__ wt,   // [27][64][64] bf16 (cout-major)
    unsigned short* __restrict__ y,          // [n][64] bf16 (raw conv out)
    float* __restrict__ pS,                  // [64][grid] transposed partials
    float* __restrict__ pQ,                  // [64][grid]
    int n)
{
    __shared__ unsigned short Atile[3][4096];   // 3 x (64 rows x 64 shorts) = 24 KB
    __shared__ int lidx[27 * 64];               // neighbor indices (6.9 KB)

    const int tid  = threadIdx.x;
    const int wid  = tid >> 6;
    const int lane = tid & 63;
    const int lr   = lane & 15;
    const int lg   = lane >> 4;
    const int base = blockIdx.x * 64;

    // stage neighbor indices; after this, idx reads are LDS-only (out of vmcnt queue)
    for (int j = tid; j < 27 * 64; j += 256) {
        int row = j / 27;
        int kk  = j - row * 27;
        int gr  = base + row; if (gr >= n) gr = n - 1;
        lidx[j] = nh[(size_t)gr * 27 + kk];
    }
    __syncthreads();   // full drain: vmcnt queue empty entering the pipeline

    // staging geometry: rows (tid>>3) [+32], 16B slot (tid&7), XOR-swizzled source
    const int srow = tid >> 3;
    const int xoff = ((tid & 7) ^ (srow & 7)) * 8;
    const int so0  = srow * 27;
    const int so1  = (srow + 32) * 27;

    f32x4 acc[4];
    #pragma unroll
    for (int t = 0; t < 4; ++t) acc[t] = (f32x4){0.f, 0.f, 0.f, 0.f};

    const unsigned short* wB = wt + (wid * 16 + lr) * 64 + lg * 8;
    bf16x8 Ba0, Ba1, Bb0, Bb1, Bc0, Bc1;   // 3 named B-pairs: compile-time, no arrays

#define ISSUE(kk, BUF, B0, B1) do {                                                   \
        const int i0_ = lidx[so0 + (kk)];                                             \
        const int i1_ = lidx[so1 + (kk)];                                             \
        B0 = *reinterpret_cast<const bf16x8*>(wB + (size_t)(kk) * 4096);              \
        B1 = *reinterpret_cast<const bf16x8*>(wB + (size_t)(kk) * 4096 + 32);         \
        __builtin_amdgcn_global_load_lds(                                             \
            (const __attribute__((address_space(1))) unsigned int*)(xb + (size_t)i0_ * 64 + xoff), \
            (__attribute__((address_space(3))) unsigned int*)(&Atile[BUF][wid * 512]), 16, 0, 0);    \
        __builtin_amdgcn_global_load_lds(                                             \
            (const __attribute__((address_space(1))) unsigned int*)(xb + (size_t)i1_ * 64 + xoff), \
            (__attribute__((address_space(3))) unsigned int*)(&Atile[BUF][2048 + wid * 512]), 16, 0, 0); \
    } while (0)

#define PHASE(BUF, B0, B1, VMSTR) do {                                                \
        asm volatile("s_waitcnt " VMSTR ::: "memory");                                \
        __builtin_amdgcn_s_barrier();                                                 \
        __builtin_amdgcn_sched_barrier(0);                                            \
        const unsigned short* At = &Atile[BUF][0];                                    \
        _Pragma("unroll")                                                             \
        for (int t = 0; t < 4; ++t) {                                                 \
            const int row_ = t * 16 + lr;                                             \
            const int sw_  = (row_ & 7) * 8;                                          \
            bf16x8 A0 = *reinterpret_cast<const bf16x8*>(&At[row_ * 64 + ((lg * 8) ^ sw_)]);        \
            bf16x8 A1 = *reinterpret_cast<const bf16x8*>(&At[row_ * 64 + (((4 + lg) * 8) ^ sw_)]);  \
            acc[t] = __builtin_amdgcn_mfma_f32_16x16x32_bf16(A0, B0, acc[t], 0, 0, 0); \
            acc[t] = __builtin_amdgcn_mfma_f32_16x16x32_bf16(A1, B1, acc[t], 0, 0, 0); \
        }                                                                             \
        asm volatile("s_waitcnt lgkmcnt(0)" ::: "memory");                            \
        __builtin_amdgcn_sched_barrier(0);                                            \
        __builtin_amdgcn_s_barrier();                                                 \
    } while (0)

    // prologue: taps 0,1 in flight (8 VMEM ops)
    ISSUE(0, 0, Ba0, Ba1);
    ISSUE(1, 1, Bb0, Bb1);

    #pragma unroll 1
    for (int k = 0; k < 24; k += 3) {
        ISSUE(k + 2, 2, Bc0, Bc1);
        PHASE(0, Ba0, Ba1, "vmcnt(8)");    // retire tap k; k+1,k+2 in flight
        ISSUE(k + 3, 0, Ba0, Ba1);
        PHASE(1, Bb0, Bb1, "vmcnt(8)");
        ISSUE(k + 4, 1, Bb0, Bb1);
        PHASE(2, Bc0, Bc1, "vmcnt(8)");
    }
    // tail: taps 24,25 in flight
    ISSUE(26, 2, Bc0, Bc1);
    PHASE(0, Ba0, Ba1, "vmcnt(8)");
    PHASE(1, Bb0, Bb1, "vmcnt(4)");
    PHASE(2, Bc0, Bc1, "vmcnt(0)");
#undef ISSUE
#undef PHASE

    // epilogue: store bf16 conv output + per-channel partial stats (round-3 proven)
    float s1 = 0.f, s2 = 0.f;
    #pragma unroll
    for (int t = 0; t < 4; ++t) {
        #pragma unroll
        for (int rg = 0; rg < 4; ++rg) {
            const int row = base + t * 16 + lg * 4 + rg;   // C/D: row=(lane>>4)*4+reg
            const float v = acc[t][rg];
            if (row < n) {
                s1 += v;
                s2 += v * v;
                y[(size_t)row * 64 + wid * 16 + lr] = f2bf(v);   // col = wid*16 + (lane&15)
            }
        }
    }
    s1 += __shfl_xor(s1, 16); s1 += __shfl_xor(s1, 32);
    s2 += __shfl_xor(s2, 16); s2 += __shfl_xor(s2, 32);
    if (lane < 16) {
        const int ch = wid * 16 + lane;
        pS[(size_t)ch * gridDim.x + blockIdx.x] = s1;
        pQ[(size_t)ch * gridDim.x + blockIdx.x] = s2;
    }
}

// ---------------- BN finalize: parallel reduce of partials ----------------
__global__ __launch_bounds__(256) void bn_stats_kernel(
        const float* __restrict__ pS, const float* __restrict__ pQ,
        const float* __restrict__ gamma, const float* __restrict__ beta,
        float* __restrict__ bnp, int nb, float invN) {
    const int c = blockIdx.x;          // channel
    const int tid = threadIdx.x;
    float S = 0.f, Q = 0.f;
    for (int b = tid; b < nb; b += 256) {
        S += pS[(size_t)c * nb + b];
        Q += pQ[(size_t)c * nb + b];
    }
    #pragma unroll
    for (int o = 1; o < 64; o <<= 1) {
        S += __shfl_xor(S, o);
        Q += __shfl_xor(Q, o);
    }
    __shared__ float sh[8];
    if ((tid & 63) == 0) { sh[(tid >> 6) * 2] = S; sh[(tid >> 6) * 2 + 1] = Q; }
    __syncthreads();
    if (tid == 0) {
        S = sh[0] + sh[2] + sh[4] + sh[6];
        Q = sh[1] + sh[3] + sh[5] + sh[7];
        const float mean = S * invN;
        const float var  = Q * invN - mean * mean;
        const float sc   = gamma[c] * rsqrtf(var + 1e-5f);
        bnp[c]      = sc;
        bnp[64 + c] = beta[c] - mean * sc;
    }
}

// ---------------- BN+ReLU -> bf16 (input of conv2) ----------------
__global__ void bn_relu_kernel(const unsigned short* __restrict__ y, const float* __restrict__ bnp,
                               unsigned short* __restrict__ yn, int total8) {
    int i = blockIdx.x * blockDim.x + threadIdx.x;
    if (i >= total8) return;
    bf16x8 v = reinterpret_cast<const bf16x8*>(y)[i];
    int c0 = (i * 8) & 63;
    bf16x8 o;
    #pragma unroll
    for (int j = 0; j < 8; ++j) {
        float f = bf2f((unsigned short)v[j]) * bnp[c0 + j] + bnp[64 + c0 + j];
        f = fmaxf(f, 0.f);
        o[j] = (short)f2bf(f);
    }
    reinterpret_cast<bf16x8*>(yn)[i] = o;
}

// ---------------- final: BN2 + residual + ReLU -> f32 out, plus depth ----------------
__global__ void final_kernel(const unsigned short* __restrict__ y2, const float* __restrict__ x,
                             const float* __restrict__ bnp, const int* __restrict__ depth,
                             float* __restrict__ out, int total8, int n) {
    int i = blockIdx.x * blockDim.x + threadIdx.x;
    if (i == 0) out[(size_t)n * 64] = (float)depth[0];
    if (i >= total8) return;
    bf16x8 v = reinterpret_cast<const bf16x8*>(y2)[i];
    const float4* xp = reinterpret_cast<const float4*>(x) + (size_t)i * 2;
    float4 xa = xp[0], xbv = xp[1];
    int c0 = (i * 8) & 63;
    float r[8];
    #pragma unroll
    for (int j = 0; j < 8; ++j)
        r[j] = bf2f((unsigned short)v[j]) * bnp[c0 + j] + bnp[64 + c0 + j];
    r[0] += xa.x;  r[1] += xa.y;  r[2] += xa.z;  r[3] += xa.w;
    r[4] += xbv.x; r[5] += xbv.y; r[6] += xbv.z; r[7] += xbv.w;
    float4* op = reinterpret_cast<float4*>(out) + (size_t)i * 2;
    float4 o0 = {fmaxf(r[0], 0.f), fmaxf(r[1], 0.f), fmaxf(r[2], 0.f), fmaxf(r[3], 0.f)};
    float4 o1 = {fmaxf(r[4], 0.f), fmaxf(r[5], 0.f), fmaxf(r[6], 0.f), fmaxf(r[7], 0.f)};
    op[0] = o0;
    op[1] = o1;
}

extern "C" void kernel_launch(void* const* d_in, const int* in_sizes, int n_in,
                              void* d_out, int out_size, void* d_ws, size_t ws_size,
                              hipStream_t stream) {
    const float* x     = (const float*)d_in[0];
    const int*   neigh = (const int*)d_in[1];
    const int*   depth = (const int*)d_in[2];
    const float* W1    = (const float*)d_in[3];
    const float* g1    = (const float*)d_in[4];
    const float* b1    = (const float*)d_in[5];
    const float* W2    = (const float*)d_in[6];
    const float* g2    = (const float*)d_in[7];
    const float* b2    = (const float*)d_in[8];
    float* out = (float*)d_out;

    const int n      = in_sizes[0] / 64;   // 200000
    const int total8 = in_sizes[0] / 8;    // N*C/8
    const int nb     = (n + 63) / 64;      // conv grid (3125)

    char* ws = (char*)d_ws;
    size_t off = 0;
    auto carve = [&](size_t bytes) -> char* {
        char* p = ws + off;
        off += (bytes + 255) & ~((size_t)255);
        return p;
    };
    unsigned short* bufA = (unsigned short*)carve((size_t)n * 64 * 2); // xb, later y1n
    unsigned short* bufB = (unsigned short*)carve((size_t)n * 64 * 2); // y1, later y2
    unsigned short* w1t  = (unsigned short*)carve(27 * 4096 * 2);
    unsigned short* w2t  = (unsigned short*)carve(27 * 4096 * 2);
    float*          pS   = (float*)carve((size_t)nb * 64 * 4);
    float*          pQ   = (float*)carve((size_t)nb * 64 * 4);
    float*          bnp1 = (float*)carve(128 * 4);
    float*          bnp2 = (float*)carve(128 * 4);

    const int gcvt = (total8 + 255) / 256;
    const int gw   = (2 * 27 * 4096 + 255) / 256;
    const float invN = 1.0f / (float)n;

    cvt_x_kernel<<<gcvt, 256, 0, stream>>>(x, bufA, total8);
    cvt_w_kernel<<<gw, 256, 0, stream>>>(W1, W2, w1t, w2t);

    conv_mfma<<<nb, 256, 0, stream>>>(bufA, neigh, w1t, bufB, pS, pQ, n);
    bn_stats_kernel<<<64, 256, 0, stream>>>(pS, pQ, g1, b1, bnp1, nb, invN);
    bn_relu_kernel<<<gcvt, 256, 0, stream>>>(bufB, bnp1, bufA, total8);

    conv_mfma<<<nb, 256, 0, stream>>>(bufA, neigh, w2t, bufB, pS, pQ, n);
    bn_stats_kernel<<<64, 256, 0, stream>>>(pS, pQ, g2, b2, bnp2, nb, invN);
    final_kernel<<<gcvt, 256, 0, stream>>>(bufB, x, bnp2, depth, out, total8, n);
}

// Round 7
// 278.589 us; speedup vs baseline: 1.5427x; 1.0139x over previous
//
#include <hip/hip_runtime.h>

typedef __attribute__((ext_vector_type(8))) short bf16x8;
typedef __attribute__((ext_vector_type(4))) float f32x4;

static __device__ __forceinline__ unsigned short f2bf(float f) {
    unsigned int u = __builtin_bit_cast(unsigned int, f);
    u += 0x7fffu + ((u >> 16) & 1u);          // round-to-nearest-even
    return (unsigned short)(u >> 16);
}
static __device__ __forceinline__ float bf2f(unsigned short h) {
    unsigned int u = ((unsigned int)h) << 16;
    return __builtin_bit_cast(float, u);
}

// ---------------- prep: x->bf16 and W->WT bf16, single launch ----------------
__global__ void cvt_xw_kernel(const float* __restrict__ x, unsigned short* __restrict__ xb, int total8, int gx,
                              const float* __restrict__ w1, const float* __restrict__ w2,
                              unsigned short* __restrict__ wt1, unsigned short* __restrict__ wt2) {
    if ((int)blockIdx.x < gx) {
        int i = blockIdx.x * 256 + threadIdx.x;
        if (i >= total8) return;
        const float4* p = reinterpret_cast<const float4*>(x) + (size_t)i * 2;
        float4 a = p[0], b = p[1];
        bf16x8 o;
        o[0] = (short)f2bf(a.x); o[1] = (short)f2bf(a.y); o[2] = (short)f2bf(a.z); o[3] = (short)f2bf(a.w);
        o[4] = (short)f2bf(b.x); o[5] = (short)f2bf(b.y); o[6] = (short)f2bf(b.z); o[7] = (short)f2bf(b.w);
        reinterpret_cast<bf16x8*>(xb)[i] = o;
    } else {
        int i = (blockIdx.x - gx) * 256 + threadIdx.x;
        if (i >= 2 * 27 * 4096) return;
        const float* w = (i < 27 * 4096) ? w1 : w2;
        unsigned short* wt = (i < 27 * 4096) ? wt1 : wt2;
        int j = (i < 27 * 4096) ? i : i - 27 * 4096;
        int k = j >> 12;
        int cout = (j >> 6) & 63;
        int cin = j & 63;
        wt[j] = f2bf(w[((size_t)(k * 64 + cin)) * 64 + cout]);
    }
}

// ---------------- gathered GEMM (octree conv), depth-2, rolled modulo-scheduled ----------------
// Block = 64 rows x 64 cols. 4 waves; wave w owns col-quarter w*16..w*16+15.
// 3 LDS A-buffers + 3 named B-reg pairs; prefetch distance 2. ISSUE = 4 VMEM ops
// (2 B-frag loads then 2 global_load_lds); steady-state wait = vmcnt(8); tail 8/4/0.
// Loop stays ROLLED (rounds 4/5 showed full unroll kills I-cache).
// Epilogue: LDS-transpose (XOR-chunk swizzle) -> coalesced 16B/lane y stores.
__global__ __launch_bounds__(256, 5) void conv_mfma(
    const unsigned short* __restrict__ xb,   // [n][64] bf16
    const int* __restrict__ nh,              // [n][27] neighbor indices
    const unsigned short* __restrict__ wt,   // [27][64][64] bf16 (cout-major)
    unsigned short* __restrict__ y,          // [n][64] bf16 (raw conv out)
    float* __restrict__ pS,                  // [64][grid] transposed partials
    float* __restrict__ pQ,                  // [64][grid]
    int n)
{
    __shared__ unsigned short Atile[3][4096];   // 3 x (64 rows x 64 shorts) = 24 KB
    __shared__ int lidx[27 * 64];               // neighbor indices (6.9 KB)

    const int tid  = threadIdx.x;
    const int wid  = tid >> 6;
    const int lane = tid & 63;
    const int lr   = lane & 15;
    const int lg   = lane >> 4;
    const int base = blockIdx.x * 64;

    // stage neighbor indices; after this, idx reads are LDS-only (out of vmcnt queue)
    for (int j = tid; j < 27 * 64; j += 256) {
        int row = j / 27;
        int kk  = j - row * 27;
        int gr  = base + row; if (gr >= n) gr = n - 1;
        lidx[j] = nh[(size_t)gr * 27 + kk];
    }
    __syncthreads();   // full drain: vmcnt queue empty entering the pipeline

    // staging geometry: rows (tid>>3) [+32], 16B slot (tid&7), XOR-swizzled source
    const int srow = tid >> 3;
    const int xoff = ((tid & 7) ^ (srow & 7)) * 8;
    const int so0  = srow * 27;
    const int so1  = (srow + 32) * 27;

    f32x4 acc[4];
    #pragma unroll
    for (int t = 0; t < 4; ++t) acc[t] = (f32x4){0.f, 0.f, 0.f, 0.f};

    const unsigned short* wB = wt + (wid * 16 + lr) * 64 + lg * 8;
    bf16x8 Ba0, Ba1, Bb0, Bb1, Bc0, Bc1;   // 3 named B-pairs: compile-time, no arrays

#define ISSUE(kk, BUF, B0, B1) do {                                                   \
        const int i0_ = lidx[so0 + (kk)];                                             \
        const int i1_ = lidx[so1 + (kk)];                                             \
        B0 = *reinterpret_cast<const bf16x8*>(wB + (size_t)(kk) * 4096);              \
        B1 = *reinterpret_cast<const bf16x8*>(wB + (size_t)(kk) * 4096 + 32);         \
        __builtin_amdgcn_global_load_lds(                                             \
            (const __attribute__((address_space(1))) unsigned int*)(xb + (size_t)i0_ * 64 + xoff), \
            (__attribute__((address_space(3))) unsigned int*)(&Atile[BUF][wid * 512]), 16, 0, 0);    \
        __builtin_amdgcn_global_load_lds(                                             \
            (const __attribute__((address_space(1))) unsigned int*)(xb + (size_t)i1_ * 64 + xoff), \
            (__attribute__((address_space(3))) unsigned int*)(&Atile[BUF][2048 + wid * 512]), 16, 0, 0); \
    } while (0)

#define PHASE(BUF, B0, B1, VMSTR) do {                                                \
        asm volatile("s_waitcnt " VMSTR ::: "memory");                                \
        __builtin_amdgcn_s_barrier();                                                 \
        __builtin_amdgcn_sched_barrier(0);                                            \
        const unsigned short* At = &Atile[BUF][0];                                    \
        _Pragma("unroll")                                                             \
        for (int t = 0; t < 4; ++t) {                                                 \
            const int row_ = t * 16 + lr;                                             \
            const int sw_  = (row_ & 7) * 8;                                          \
            bf16x8 A0 = *reinterpret_cast<const bf16x8*>(&At[row_ * 64 + ((lg * 8) ^ sw_)]);        \
            bf16x8 A1 = *reinterpret_cast<const bf16x8*>(&At[row_ * 64 + (((4 + lg) * 8) ^ sw_)]);  \
            acc[t] = __builtin_amdgcn_mfma_f32_16x16x32_bf16(A0, B0, acc[t], 0, 0, 0); \
            acc[t] = __builtin_amdgcn_mfma_f32_16x16x32_bf16(A1, B1, acc[t], 0, 0, 0); \
        }                                                                             \
        asm volatile("s_waitcnt lgkmcnt(0)" ::: "memory");                            \
        __builtin_amdgcn_sched_barrier(0);                                            \
        __builtin_amdgcn_s_barrier();                                                 \
    } while (0)

    // prologue: taps 0,1 in flight (8 VMEM ops)
    ISSUE(0, 0, Ba0, Ba1);
    ISSUE(1, 1, Bb0, Bb1);

    #pragma unroll 1
    for (int k = 0; k < 24; k += 3) {
        ISSUE(k + 2, 2, Bc0, Bc1);
        PHASE(0, Ba0, Ba1, "vmcnt(8)");    // retire tap k; k+1,k+2 in flight
        ISSUE(k + 3, 0, Ba0, Ba1);
        PHASE(1, Bb0, Bb1, "vmcnt(8)");
        ISSUE(k + 4, 1, Bb0, Bb1);
        PHASE(2, Bc0, Bc1, "vmcnt(8)");
    }
    // tail: taps 24,25 in flight
    ISSUE(26, 2, Bc0, Bc1);
    PHASE(0, Ba0, Ba1, "vmcnt(8)");
    PHASE(1, Bb0, Bb1, "vmcnt(4)");
    PHASE(2, Bc0, Bc1, "vmcnt(0)");
#undef ISSUE
#undef PHASE

    // ---- per-channel partial stats from accumulators (unchanged path) ----
    float s1 = 0.f, s2 = 0.f;
    #pragma unroll
    for (int t = 0; t < 4; ++t) {
        #pragma unroll
        for (int rg = 0; rg < 4; ++rg) {
            const int row = base + t * 16 + lg * 4 + rg;   // C/D: row=(lane>>4)*4+reg
            if (row < n) {
                const float v = acc[t][rg];
                s1 += v;
                s2 += v * v;
            }
        }
    }
    s1 += __shfl_xor(s1, 16); s1 += __shfl_xor(s1, 32);
    s2 += __shfl_xor(s2, 16); s2 += __shfl_xor(s2, 32);
    if (lane < 16) {
        const int ch = wid * 16 + lane;
        pS[(size_t)ch * gridDim.x + blockIdx.x] = s1;
        pQ[(size_t)ch * gridDim.x + blockIdx.x] = s2;
    }

    // ---- y store: transpose through LDS (chunk-XOR swizzle), coalesced 16B/lane ----
    // last PHASE ended with lgkmcnt(0)+barrier -> Atile dead, safe to reuse.
    unsigned short* yt = &Atile[0][0];   // [64 rows][64 shorts]
    #pragma unroll
    for (int t = 0; t < 4; ++t) {
        #pragma unroll
        for (int rg = 0; rg < 4; ++rg) {
            const int row = t * 16 + lg * 4 + rg;                 // block-local row
            const int ch  = (wid * 2 + (lr >> 3)) ^ (row & 7);    // swizzled 16B chunk
            yt[row * 64 + ch * 8 + (lr & 7)] = f2bf(acc[t][rg]);
        }
    }
    __syncthreads();
    {
        const int r0 = tid >> 3;          // 0..31
        const int j  = tid & 7;           // 16B chunk within row
        const int g0 = base + r0;
        const int g1 = base + 32 + r0;
        bf16x8 v0 = *reinterpret_cast<const bf16x8*>(&yt[r0 * 64 + ((j ^ (r0 & 7)) * 8)]);
        if (g0 < n) *reinterpret_cast<bf16x8*>(&y[(size_t)g0 * 64 + j * 8]) = v0;
        bf16x8 v1 = *reinterpret_cast<const bf16x8*>(&yt[(32 + r0) * 64 + ((j ^ (r0 & 7)) * 8)]);
        if (g1 < n) *reinterpret_cast<bf16x8*>(&y[(size_t)g1 * 64 + j * 8]) = v1;
    }
}

// ---------------- BN finalize: parallel reduce of partials ----------------
__global__ __launch_bounds__(256) void bn_stats_kernel(
        const float* __restrict__ pS, const float* __restrict__ pQ,
        const float* __restrict__ gamma, const float* __restrict__ beta,
        float* __restrict__ bnp, int nb, float invN) {
    const int c = blockIdx.x;          // channel
    const int tid = threadIdx.x;
    float S = 0.f, Q = 0.f;
    for (int b = tid; b < nb; b += 256) {
        S += pS[(size_t)c * nb + b];
        Q += pQ[(size_t)c * nb + b];
    }
    #pragma unroll
    for (int o = 1; o < 64; o <<= 1) {
        S += __shfl_xor(S, o);
        Q += __shfl_xor(Q, o);
    }
    __shared__ float sh[8];
    if ((tid & 63) == 0) { sh[(tid >> 6) * 2] = S; sh[(tid >> 6) * 2 + 1] = Q; }
    __syncthreads();
    if (tid == 0) {
        S = sh[0] + sh[2] + sh[4] + sh[6];
        Q = sh[1] + sh[3] + sh[5] + sh[7];
        const float mean = S * invN;
        const float var  = Q * invN - mean * mean;
        const float sc   = gamma[c] * rsqrtf(var + 1e-5f);
        bnp[c]      = sc;
        bnp[64 + c] = beta[c] - mean * sc;
    }
}

// ---------------- BN+ReLU -> bf16 (input of conv2) ----------------
__global__ void bn_relu_kernel(const unsigned short* __restrict__ y, const float* __restrict__ bnp,
                               unsigned short* __restrict__ yn, int total8) {
    int i = blockIdx.x * blockDim.x + threadIdx.x;
    if (i >= total8) return;
    bf16x8 v = reinterpret_cast<const bf16x8*>(y)[i];
    int c0 = (i * 8) & 63;
    bf16x8 o;
    #pragma unroll
    for (int j = 0; j < 8; ++j) {
        float f = bf2f((unsigned short)v[j]) * bnp[c0 + j] + bnp[64 + c0 + j];
        f = fmaxf(f, 0.f);
        o[j] = (short)f2bf(f);
    }
    reinterpret_cast<bf16x8*>(yn)[i] = o;
}

// ---------------- final: BN2 + residual + ReLU -> f32 out, plus depth ----------------
__global__ void final_kernel(const unsigned short* __restrict__ y2, const float* __restrict__ x,
                             const float* __restrict__ bnp, const int* __restrict__ depth,
                             float* __restrict__ out, int total8, int n) {
    int i = blockIdx.x * blockDim.x + threadIdx.x;
    if (i == 0) out[(size_t)n * 64] = (float)depth[0];
    if (i >= total8) return;
    bf16x8 v = reinterpret_cast<const bf16x8*>(y2)[i];
    const float4* xp = reinterpret_cast<const float4*>(x) + (size_t)i * 2;
    float4 xa = xp[0], xbv = xp[1];
    int c0 = (i * 8) & 63;
    float r[8];
    #pragma unroll
    for (int j = 0; j < 8; ++j)
        r[j] = bf2f((unsigned short)v[j]) * bnp[c0 + j] + bnp[64 + c0 + j];
    r[0] += xa.x;  r[1] += xa.y;  r[2] += xa.z;  r[3] += xa.w;
    r[4] += xbv.x; r[5] += xbv.y; r[6] += xbv.z; r[7] += xbv.w;
    float4* op = reinterpret_cast<float4*>(out) + (size_t)i * 2;
    float4 o0 = {fmaxf(r[0], 0.f), fmaxf(r[1], 0.f), fmaxf(r[2], 0.f), fmaxf(r[3], 0.f)};
    float4 o1 = {fmaxf(r[4], 0.f), fmaxf(r[5], 0.f), fmaxf(r[6], 0.f), fmaxf(r[7], 0.f)};
    op[0] = o0;
    op[1] = o1;
}

extern "C" void kernel_launch(void* const* d_in, const int* in_sizes, int n_in,
                              void* d_out, int out_size, void* d_ws, size_t ws_size,
                              hipStream_t stream) {
    const float* x     = (const float*)d_in[0];
    const int*   neigh = (const int*)d_in[1];
    const int*   depth = (const int*)d_in[2];
    const float* W1    = (const float*)d_in[3];
    const float* g1    = (const float*)d_in[4];
    const float* b1    = (const float*)d_in[5];
    const float* W2    = (const float*)d_in[6];
    const float* g2    = (const float*)d_in[7];
    const float* b2    = (const float*)d_in[8];
    float* out = (float*)d_out;

    const int n      = in_sizes[0] / 64;   // 200000
    const int total8 = in_sizes[0] / 8;    // N*C/8
    const int nb     = (n + 63) / 64;      // conv grid (3125)

    char* ws = (char*)d_ws;
    size_t off = 0;
    auto carve = [&](size_t bytes) -> char* {
        char* p = ws + off;
        off += (bytes + 255) & ~((size_t)255);
        return p;
    };
    unsigned short* bufA = (unsigned short*)carve((size_t)n * 64 * 2); // xb, later y1n
    unsigned short* bufB = (unsigned short*)carve((size_t)n * 64 * 2); // y1, later y2
    unsigned short* w1t  = (unsigned short*)carve(27 * 4096 * 2);
    unsigned short* w2t  = (unsigned short*)carve(27 * 4096 * 2);
    float*          pS   = (float*)carve((size_t)nb * 64 * 4);
    float*          pQ   = (float*)carve((size_t)nb * 64 * 4);
    float*          bnp1 = (float*)carve(128 * 4);
    float*          bnp2 = (float*)carve(128 * 4);

    const int gx   = (total8 + 255) / 256;
    const int gw   = (2 * 27 * 4096 + 255) / 256;
    const float invN = 1.0f / (float)n;

    cvt_xw_kernel<<<gx + gw, 256, 0, stream>>>(x, bufA, total8, gx, W1, W2, w1t, w2t);

    conv_mfma<<<nb, 256, 0, stream>>>(bufA, neigh, w1t, bufB, pS, pQ, n);
    bn_stats_kernel<<<64, 256, 0, stream>>>(pS, pQ, g1, b1, bnp1, nb, invN);
    bn_relu_kernel<<<gx, 256, 0, stream>>>(bufB, bnp1, bufA, total8);

    conv_mfma<<<nb, 256, 0, stream>>>(bufA, neigh, w2t, bufB, pS, pQ, n);
    bn_stats_kernel<<<64, 256, 0, stream>>>(pS, pQ, g2, b2, bnp2, nb, invN);
    final_kernel<<<gx, 256, 0, stream>>>(bufB, x, bnp2, depth, out, total8, n);
}